// Round 12
// baseline (252.287 us; speedup 1.0000x reference)
//
#include <hip/hip_runtime.h>

typedef short bf16x8 __attribute__((ext_vector_type(8)));
typedef float f32x4 __attribute__((ext_vector_type(4)));
typedef unsigned short u16;
typedef unsigned int u32;

static __device__ __forceinline__ u16 f2bf(float f) {
  u32 u = __builtin_bit_cast(u32, f);
  u32 r = (u + 0x7FFFu + ((u >> 16) & 1u)) >> 16;  // RNE
  return (u16)r;
}

// ---- kernel 0: one-time f32 -> bf16 weight conversion + FRAGMENT SWIZZLE ----
// wqkv chunks (cid < 24576): tile = cid>>9 (tile = s*16+h*2+u), k = (cid>>6)&7,
//   lane = cid&63; 16B chunk = W[tile*16+(lane&15)][k*32+(lane>>4)*8 .. +8],
//   stored at wbf + cid*8 (linear).
// wproj (pid < 8192): mt = pid>>9, h = (pid>>6)&7, lane = pid&63 — stored
//   HEAD-MAJOR: dst chunk = 24576 + h*1024 + mt*64 + lane.
__global__ __launch_bounds__(256) void k_conv(
    const float* __restrict__ wqkv, const float* __restrict__ wproj,
    u16* __restrict__ wbf) {
  const int cid = blockIdx.x * 256 + threadIdx.x;  // 128 blocks -> 32768 chunks
  const float* src;
  int dst;
  if (cid < 24576) {
    const int tile = cid >> 9, rem = cid & 511;
    const int k = rem >> 6, lane = rem & 63;
    src = wqkv + (size_t)(tile * 16 + (lane & 15)) * 256 + k * 32 + (lane >> 4) * 8;
    dst = cid;
  } else {
    const int pid = cid - 24576;
    const int mt = pid >> 9, rem = pid & 511;
    const int h = rem >> 6, lane = rem & 63;
    src = wproj + (size_t)(mt * 16 + (lane & 15)) * 256 + h * 32 + (lane >> 4) * 8;
    dst = 24576 + h * 1024 + mt * 64 + lane;
  }
  float4 f0 = *(const float4*)(src);
  float4 f1 = *(const float4*)(src + 4);
  ushort4 a, b;
  a.x = f2bf(f0.x); a.y = f2bf(f0.y); a.z = f2bf(f0.z); a.w = f2bf(f0.w);
  b.x = f2bf(f1.x); b.y = f2bf(f1.y); b.z = f2bf(f1.z); b.w = f2bf(f1.w);
  *(ushort4*)(wbf + (size_t)dst * 8) = a;
  *(ushort4*)(wbf + (size_t)dst * 8 + 4) = b;
}

// v11: v9 k_fused (confirmed 98 us, dense Obuf writes) + OCCUPANCY-FIXED
// k_proj. R11's null (dense-LDS epilogue = co-timed scatter) proved k_proj is
// latency-bound, not write-bound: 1 block/CU at ~200 VGPR in front of L3-
// latency Obuf reads. Fix: split (b,wh,ch) further by pos-half -> 512 blocks,
// accP[8][2]=64 regs, __launch_bounds__(512,4) caps 128 VGPR -> 2 blocks/CU,
// 16 waves/CU, all blocks co-resident. Same MFMA order -> bit-identical sums.
//
// k_fused LDS (u16): QH 0 (64x40) | KH 2560 | VTH 5120 (32x72) | PH 7424
//   X [64][264] overlays [0,16896) in phase 1.
#define QH 0
#define KH 2560
#define VTH 5120
#define PH 7424
#define LDS_TOT 16896
#define OBUF_OFF 262144  // u16 offset of Obuf in workspace (after 512KB wbf)

#define MEMF() asm volatile("" ::: "memory")
#define BAR()                        \
  do {                               \
    MEMF();                          \
    __builtin_amdgcn_s_barrier();    \
    MEMF();                          \
  } while (0)
#define WLG0() asm volatile("s_waitcnt lgkmcnt(0)" ::: "memory")

// load one tile's 8 B-fragments into a register array (b128 from L2)
#define LOADF(FR, TI)                                              \
  do {                                                             \
    const u16* fp_ = wbf + (size_t)(TI) * 4096 + lane * 8;         \
    _Pragma("unroll") for (int k = 0; k < 8; ++k)                  \
        FR[k] = *(const bf16x8*)(fp_ + k * 512);                   \
  } while (0)

// one 16-c_out tile x 32 own pos rows from register frags (2 indep chains)
#define GEMM_TILE_F(FR, DSTB, U)                                              \
  do {                                                                        \
    f32x4 a0 = {0.f, 0.f, 0.f, 0.f}, a1 = {0.f, 0.f, 0.f, 0.f};               \
    _Pragma("unroll") for (int k = 0; k < 8; ++k) {                           \
      a0 = __builtin_amdgcn_mfma_f32_16x16x32_bf16(af0[k], FR[k], a0, 0, 0, 0);\
      a1 = __builtin_amdgcn_mfma_f32_16x16x32_bf16(af1[k], FR[k], a1, 0, 0, 0);\
    }                                                                         \
    _Pragma("unroll") for (int r = 0; r < 4; ++r) {                           \
      LDS[(DSTB) + (wp * 32 + quad * 4 + r) * 40 + (U) * 16 + l15] =          \
          f2bf(a0[r]);                                                        \
      LDS[(DSTB) + (wp * 32 + 16 + quad * 4 + r) * 40 + (U) * 16 + l15] =     \
          f2bf(a1[r]);                                                        \
    }                                                                         \
  } while (0)

// V tile -> VTH transposed [hd][pos], from register frags
#define V_TILE_F(FR, U)                                                       \
  do {                                                                        \
    f32x4 a0 = {0.f, 0.f, 0.f, 0.f}, a1 = {0.f, 0.f, 0.f, 0.f};               \
    _Pragma("unroll") for (int k = 0; k < 8; ++k) {                           \
      a0 = __builtin_amdgcn_mfma_f32_16x16x32_bf16(af0[k], FR[k], a0, 0, 0, 0);\
      a1 = __builtin_amdgcn_mfma_f32_16x16x32_bf16(af1[k], FR[k], a1, 0, 0, 0);\
    }                                                                         \
    ushort4 pk0, pk1;                                                         \
    pk0.x = f2bf(a0[0]); pk0.y = f2bf(a0[1]);                                 \
    pk0.z = f2bf(a0[2]); pk0.w = f2bf(a0[3]);                                 \
    pk1.x = f2bf(a1[0]); pk1.y = f2bf(a1[1]);                                 \
    pk1.z = f2bf(a1[2]); pk1.w = f2bf(a1[3]);                                 \
    *(ushort4*)&LDS[VTH + ((U) * 16 + l15) * 72 + wp * 32 + quad * 4] = pk0;  \
    *(ushort4*)&LDS[VTH + ((U) * 16 + l15) * 72 + wp * 32 + 16 + quad * 4] =  \
        pk1;                                                                  \
  } while (0)

// full 3-tile GEMM for head HH (wc-split, fA/fB pre-loaded)
#define GEMM_HEAD(HH)                                                         \
  do {                                                                        \
    const int t2_ = wc ? (33 + (HH) * 2) : (16 + (HH) * 2); /* V1 | K0 */     \
    if (wc == 0) GEMM_TILE_F(fA, QH, 0);                                      \
    else GEMM_TILE_F(fA, KH, 1);                                              \
    LOADF(fA, t2_);                                                           \
    if (wc == 0) GEMM_TILE_F(fB, QH, 1);                                      \
    else V_TILE_F(fB, 0);                                                     \
    if (wc == 0) GEMM_TILE_F(fA, KH, 0);                                      \
    else V_TILE_F(fA, 1);                                                     \
  } while (0)

#define LOAD_AB(HH)                                                           \
  do {                                                                        \
    const int t0_ = wc ? (17 + (HH) * 2) : ((HH) * 2);     /* K1 | Q0 */      \
    const int t1_ = wc ? (32 + (HH) * 2) : ((HH) * 2 + 1); /* V0 | Q1 */      \
    LOADF(fA, t0_);                                                           \
    LOADF(fB, t1_);                                                           \
  } while (0)

__global__ __launch_bounds__(256, 2) void k_fused(
    const float* __restrict__ x, const u16* __restrict__ wbf,
    const int* __restrict__ shiftp, u16* __restrict__ obuf) {
  __shared__ u16 LDS[LDS_TOT];
  // XCD-locality swizzle: the 8 windows sharing x cache lines (same b,wh)
  // get block IDs congruent mod 128 -> same XCD under round-robin dispatch.
  const int blk = blockIdx.x;
  const int win = ((blk & 127) << 3) | (blk >> 7);  // b*64 + wh*8 + ww
  const int b = win >> 6, wh = (win >> 3) & 7, ww = win & 7;
  const int off = (shiftp[0] != 0) ? 4 : 0;
  const int t = threadIdx.x;

  // stagger co-resident blocks to decorrelate phases
  {
    const int slot = (blk >> 8) & 3;
    if (slot == 1) __builtin_amdgcn_s_sleep(16);
    else if (slot == 2) __builtin_amdgcn_s_sleep(32);
    else if (slot == 3) __builtin_amdgcn_s_sleep(48);
  }

  // ---- phase 1: stage rolled X into LDS [pos][c] (f32 -> bf16) ----
  {
    u16* X = LDS;
    const int wr = t & 7;
    const int h = ((wh << 3) + wr + off) & 63;
    const int w0 = ((ww << 3) + off) & 63;  // 4-aligned -> no wrap inside run
    const int w1 = ((ww << 3) + off + 4) & 63;
    const int p0 = wr << 3;
#pragma unroll
    for (int it = 0; it < 8; ++it) {
      const int c = (t >> 3) + (it << 5);
      const float* src = x + ((size_t)(b * 256 + c) * 64 + h) * 64;
      float4 v0 = *(const float4*)(src + w0);
      float4 v1 = *(const float4*)(src + w1);
      X[(p0 + 0) * 264 + c] = f2bf(v0.x);
      X[(p0 + 1) * 264 + c] = f2bf(v0.y);
      X[(p0 + 2) * 264 + c] = f2bf(v0.z);
      X[(p0 + 3) * 264 + c] = f2bf(v0.w);
      X[(p0 + 4) * 264 + c] = f2bf(v1.x);
      X[(p0 + 5) * 264 + c] = f2bf(v1.y);
      X[(p0 + 6) * 264 + c] = f2bf(v1.z);
      X[(p0 + 7) * 264 + c] = f2bf(v1.w);
    }
  }
  __syncthreads();  // X ready (drains x loads)

  const int lane = t & 63, wv = t >> 6;
  const int l15 = lane & 15, quad = lane >> 4;
  const int wp = wv >> 1, wc = wv & 1;   // GEMM split: pos half x tile half
  const int apos0 = wv * 16 + quad * 4;  // attn row base (pos-split)

  // af for own 32 pos rows: two 16-row subtiles
  bf16x8 af0[8], af1[8];
#pragma unroll
  for (int k = 0; k < 8; ++k) {
    af0[k] = *(const bf16x8*)&LDS[(wp * 32 + l15) * 264 + quad * 8 + k * 32];
    af1[k] =
        *(const bf16x8*)&LDS[(wp * 32 + 16 + l15) * 264 + quad * 8 + k * 32];
  }
  WLG0();
  BAR();  // X fully read everywhere; attn region may now be written

  const float scale = 0.17677669529663687f;  // 1/sqrt(32)
  u16* Pw = LDS + PH + wv * 1152;            // per-wave P [16][72]
  u16* Ow = obuf + (size_t)win * 16384;      // O plane [64 pos][256 c] bf16
  bf16x8 fA[8], fB[8];

  LOAD_AB(0);
#pragma unroll 1
  for (int h = 0; h < 8; ++h) {
    GEMM_HEAD(h);  // writes QH/KH/VTH from fA/fB
    WLG0();
    BAR();  // QKV(h) published
    if (h < 7) LOAD_AB(h + 1);  // in flight across attn + next barrier
    {
      bf16x8 aq = *(const bf16x8*)&LDS[QH + (wv * 16 + l15) * 40 + quad * 8];
      f32x4 sc[4];
#pragma unroll
      for (int nt = 0; nt < 4; ++nt) {
        bf16x8 bk = *(const bf16x8*)&LDS[KH + (nt * 16 + l15) * 40 + quad * 8];
        f32x4 z = {0.f, 0.f, 0.f, 0.f};
        sc[nt] = __builtin_amdgcn_mfma_f32_16x16x32_bf16(aq, bk, z, 0, 0, 0);
      }
#pragma unroll
      for (int r = 0; r < 4; ++r) {
        float mx = -1e30f;
#pragma unroll
        for (int nt = 0; nt < 4; ++nt) mx = fmaxf(mx, sc[nt][r]);
        mx = fmaxf(mx, __shfl_xor(mx, 1));
        mx = fmaxf(mx, __shfl_xor(mx, 2));
        mx = fmaxf(mx, __shfl_xor(mx, 4));
        mx = fmaxf(mx, __shfl_xor(mx, 8));  // row spans the 16-lane group
        float p[4], sum = 0.f;
#pragma unroll
        for (int nt = 0; nt < 4; ++nt) {
          p[nt] = __expf((sc[nt][r] - mx) * scale);
          sum += p[nt];
        }
        sum += __shfl_xor(sum, 1);
        sum += __shfl_xor(sum, 2);
        sum += __shfl_xor(sum, 4);
        sum += __shfl_xor(sum, 8);
        const float is = 1.f / sum;
#pragma unroll
        for (int nt = 0; nt < 4; ++nt)
          Pw[(quad * 4 + r) * 72 + nt * 16 + l15] = f2bf(p[nt] * is);
      }
      // PV (P write->read same wave: DS ops are in-order per wave)
      f32x4 oa[2];
      oa[0] = (f32x4){0.f, 0.f, 0.f, 0.f};
      oa[1] = (f32x4){0.f, 0.f, 0.f, 0.f};
#pragma unroll
      for (int kk = 0; kk < 2; ++kk) {
        bf16x8 ap = *(const bf16x8*)&Pw[l15 * 72 + kk * 32 + quad * 8];
#pragma unroll
        for (int n2 = 0; n2 < 2; ++n2) {
          bf16x8 bv = *(const bf16x8*)&LDS[VTH + (n2 * 16 + l15) * 72 +
                                           kk * 32 + quad * 8];
          oa[n2] = __builtin_amdgcn_mfma_f32_16x16x32_bf16(ap, bv, oa[n2], 0, 0, 0);
        }
      }
      // O(h) -> global Obuf [pos][c] bf16: per (n2,r) a 16-lane 32B dense run;
      // head h fills bytes h*64..h*64+63 of each 512B row (same-wave co-timed)
#pragma unroll
      for (int n2 = 0; n2 < 2; ++n2)
#pragma unroll
        for (int r = 0; r < 4; ++r)
          Ow[(size_t)(apos0 + r) * 256 + h * 32 + n2 * 16 + l15] =
              f2bf(oa[n2][r]);
    }
    WLG0();
    BAR();  // all LDS reads of QH/KH/VTH done; next head may overwrite
  }
}

// ---- k_proj: out = O @ Wproj^T, window-reverse + roll fused ----
// 512 blocks x 512 threads: blk = pair + 128*(ch*2+ph), pair = b*8+wh.
// The 4 sub-blocks of one (b,wh) share a mod-8 class with the k_fused
// writers of the same windows -> same-XCD L2 hits on Obuf.
// wave = window ww; each wave: 32 pos rows (ph half) x 128 c_out (ch half).
// Same per-element MFMA/head order as v9/v10 -> bit-identical sums.
// Epilogue: direct co-timed scatter (R11 A/B: dense-LDS == scatter here).
__global__ __launch_bounds__(512, 4) void k_proj(
    const u16* __restrict__ wbf, const int* __restrict__ shiftp,
    float* __restrict__ out) {
  const int blk = blockIdx.x;
  const int pair = blk & 127, sub = blk >> 7;
  const int b = pair >> 3, wh = pair & 7, ch = sub >> 1, ph = sub & 1;
  const int off = (shiftp[0] != 0) ? 4 : 0;
  const int t = threadIdx.x, lane = t & 63, wv = t >> 6;  // wv = window ww
  const int l15 = lane & 15, quad = lane >> 4;
  const int win = b * 64 + wh * 8 + wv;
  const u16* Ob = wbf + OBUF_OFF + (size_t)win * 16384;  // [64 pos][256 c]

  f32x4 accP[8][2];  // [local mt][pos subtile within half]
#pragma unroll
  for (int mt = 0; mt < 8; ++mt) {
    accP[mt][0] = (f32x4){0.f, 0.f, 0.f, 0.f};
    accP[mt][1] = (f32x4){0.f, 0.f, 0.f, 0.f};
  }

  // fully unrolled head loop: static indices let the compiler hoist/pipeline
  // the Obuf loads (L2/L3) and weight loads (L2) across heads
#pragma unroll
  for (int h = 0; h < 8; ++h) {
    bf16x8 aw[8], bo[2];
    const u16* pp_ =
        wbf + 196608 + (size_t)h * 8192 + (size_t)ch * 4096 + lane * 8;
#pragma unroll
    for (int mt = 0; mt < 8; ++mt) aw[mt] = *(const bf16x8*)(pp_ + mt * 512);
#pragma unroll
    for (int i = 0; i < 2; ++i)
      bo[i] = *(const bf16x8*)&Ob[(size_t)(ph * 32 + i * 16 + l15) * 256 +
                                  h * 32 + quad * 8];
#pragma unroll
    for (int mt = 0; mt < 8; ++mt)
#pragma unroll
      for (int i = 0; i < 2; ++i)
        accP[mt][i] =
            __builtin_amdgcn_mfma_f32_16x16x32_bf16(aw[mt], bo[i], accP[mt][i], 0, 0, 0);
  }

  // epilogue: C[c_out][pos] -> out[b][c][h][w] with roll(+4,+4); the 8 waves
  // of this block cover ww=0..7 -> each (c,hco) row's 8 chunks are co-timed.
#pragma unroll
  for (int i = 0; i < 2; ++i) {
    const int pos = ph * 32 + i * 16 + l15;
    const int hco = ((wh << 3) + (pos >> 3) + off) & 63;
    const int wco = ((wv << 3) + (pos & 7) + off) & 63;
#pragma unroll
    for (int mt = 0; mt < 8; ++mt)
#pragma unroll
      for (int r = 0; r < 4; ++r) {
        const int c = ch * 128 + mt * 16 + quad * 4 + r;
        out[((size_t)(b * 256 + c) << 12) + (hco << 6) + wco] = accP[mt][i][r];
      }
  }
}

extern "C" void kernel_launch(void* const* d_in, const int* in_sizes, int n_in,
                              void* d_out, int out_size, void* d_ws, size_t ws_size,
                              hipStream_t stream) {
  const float* x = (const float*)d_in[0];      // [16,256,64,64] f32
  const float* wqkv = (const float*)d_in[1];   // [768,256] f32
  const float* wproj = (const float*)d_in[2];  // [256,256] f32
  const int* shiftp = (const int*)d_in[3];     // scalar
  float* outp = (float*)d_out;                 // [16,256,64,64] f32
  u16* wbf = (u16*)d_ws;  // 512 KB weights + 33.5 MB Obuf scratch
  hipLaunchKernelGGL(k_conv, dim3(128), dim3(256), 0, stream, wqkv, wproj, wbf);
  hipLaunchKernelGGL(k_fused, dim3(1024), dim3(256), 0, stream, x, wbf, shiftp,
                     wbf + OBUF_OFF);
  hipLaunchKernelGGL(k_proj, dim3(512), dim3(512), 0, stream, wbf, shiftp, outp);
}